// Round 7
// baseline (180.918 us; speedup 1.0000x reference)
//
#include <hip/hip_runtime.h>
#include <math.h>

// Problem constants (B=4, S=2048, D_MODEL=512, H=8, DQ=64)
#define BATCH 4
#define SEQ   2048
#define DM    512
#define NH    8
#define DQ    64
#define BS    (BATCH*SEQ)     // 8192 rows
#define APAD  72              // padded tile stride in gemms

// q pre-scale: 1/sqrt(64) * log2(e), so softmax uses native 2^x (v_exp_f32)
#define QSCALE 0.18033688011112042f

typedef short  short8   __attribute__((ext_vector_type(8)));
typedef float  floatx4  __attribute__((ext_vector_type(4)));
typedef float  floatx16 __attribute__((ext_vector_type(16)));
typedef unsigned short ushort8 __attribute__((ext_vector_type(8)));
typedef unsigned uintx2 __attribute__((ext_vector_type(2)));
typedef unsigned uintx4 __attribute__((ext_vector_type(4)));

// cheap bf16: round-half-up (1 add + shift). Ties-only delta vs RNE.
__device__ __forceinline__ unsigned short f2bf(float f) {
    return (unsigned short)((__float_as_uint(f) + 0x8000u) >> 16);
}
// pack two floats -> two bf16 in one u32 (lo = a, hi = b): 2 adds + 1 v_perm
__device__ __forceinline__ unsigned pack2bf(float a, float b) {
    unsigned ua = __float_as_uint(a) + 0x8000u;
    unsigned ub = __float_as_uint(b) + 0x8000u;
    return __builtin_amdgcn_perm(ub, ua, 0x07060302u);  // {ub[3],ub[2],ua[3],ua[2]}
}

// ---------------------------------------------------------------------------
// convert_w: COALESCED reads for the qkv projections (v12).
// grid (256, 4).
// ---------------------------------------------------------------------------
__global__ __launch_bounds__(256) void convert_w_kernel(
    const float* __restrict__ Wq, const float* __restrict__ Wk,
    const float* __restrict__ Wv, const float* __restrict__ Wo,
    unsigned short* __restrict__ wt, unsigned short* __restrict__ wo)
{
    const int which = blockIdx.y;
    const int idx = blockIdx.x * 256 + threadIdx.x;   // 65536 per matrix
    if (which == 3) {
        float4 v = *(const float4*)(Wo + (size_t)idx * 4);
        uint2 o;
        o.x = pack2bf(v.x, v.y);
        o.y = pack2bf(v.z, v.w);
        *(uint2*)(wo + (size_t)idx * 4) = o;
    } else {
        const float* W = (which == 0) ? Wq : (which == 1) ? Wk : Wv;
        const int n   = idx & 511;         // h*64+d  (consecutive per lane)
        const int dd0 = (idx >> 9) * 4;    // 0..508
        const int h = n >> 6, d = n & 63;
        uint2 o;
        o.x = pack2bf(W[((size_t)h * DM + dd0 + 0) * DQ + d],
                      W[((size_t)h * DM + dd0 + 1) * DQ + d]);
        o.y = pack2bf(W[((size_t)h * DM + dd0 + 2) * DQ + d],
                      W[((size_t)h * DM + dd0 + 3) * DQ + d]);
        *(uint2*)(wt + (size_t)which * (DM * DM) + (size_t)n * DM + dd0) = o;
    }
}

// ---------------------------------------------------------------------------
// qkv GEMM (v12): 64x128 tile, BK=64, K=512. 4 blocks/CU.
// Outputs:
//   which 0 -> q*QSCALE bf16 [b,h,s,d]
//   which 1 -> k bf16 FRAGMENT-MAJOR Kf  [bh][s>>5][d>>4][lane][8]
//   which 2 -> v bf16 FRAGMENT-MAJOR Vf  [bh][s>>6][(s>>5)&1][d>>5][(s>>4)&1][lane][8]
// grid (128, 4, 3), block 256 (4 waves, 2x2; wave tile 32x64).
// ---------------------------------------------------------------------------
__global__ __launch_bounds__(256) void qkv_gemm_kernel(
    const float* __restrict__ Xq, const float* __restrict__ Xk,
    const float* __restrict__ Xv, const unsigned short* __restrict__ wt,
    unsigned short* __restrict__ Oq, unsigned short* __restrict__ Ok,
    unsigned short* __restrict__ Ovt)
{
    __shared__ unsigned short As[64][APAD];
    __shared__ unsigned short Bs[128][APAD];

    const int which = blockIdx.z;
    const float* X = (which == 0) ? Xq : (which == 1) ? Xk : Xv;
    const unsigned short* Bt = wt + (size_t)which * (DM * DM);

    const int m0 = blockIdx.x * 64;
    const int n0 = blockIdx.y * 128;
    const int t = threadIdx.x, w = t >> 6, lane = t & 63;
    const int quad = lane >> 4, qr = lane & 15;
    const int arow = t >> 4;           // A staging: 16 rows/pass, 4 passes
    const int acol = (t & 15) * 4;     // float4 col
    const int brow = t >> 3;           // B staging: 32 rows/pass, 4 passes
    const int bcol = (t & 7) * 8;      // ushort8 col
    const int mw = 32 * (w >> 1), nw = 64 * (w & 1);

    floatx4 acc[2][4] = {};
    float4  areg[4];
    ushort8 breg[4];

    #pragma unroll
    for (int i = 0; i < 4; ++i)
        areg[i] = *(const float4*)(X + (size_t)(m0 + i * 16 + arow) * DM + acol);
    #pragma unroll
    for (int i = 0; i < 4; ++i)
        breg[i] = *(const ushort8*)(Bt + (size_t)(n0 + i * 32 + brow) * DM + bcol);

    for (int k0 = 0; k0 < DM; k0 += 64) {
        __syncthreads();
        #pragma unroll
        for (int i = 0; i < 4; ++i) {
            uint2 o;
            o.x = pack2bf(areg[i].x, areg[i].y);
            o.y = pack2bf(areg[i].z, areg[i].w);
            *(uint2*)&As[i * 16 + arow][acol] = o;
        }
        #pragma unroll
        for (int i = 0; i < 4; ++i)
            *(ushort8*)&Bs[i * 32 + brow][bcol] = breg[i];
        __syncthreads();

        if (k0 + 64 < DM) {
            #pragma unroll
            for (int i = 0; i < 4; ++i)
                areg[i] = *(const float4*)(X + (size_t)(m0 + i * 16 + arow) * DM + k0 + 64 + acol);
            #pragma unroll
            for (int i = 0; i < 4; ++i)
                breg[i] = *(const ushort8*)(Bt + (size_t)(n0 + i * 32 + brow) * DM + k0 + 64 + bcol);
        }

        #pragma unroll
        for (int kh = 0; kh < 2; ++kh) {
            short8 af[2], bf[4];
            #pragma unroll
            for (int si = 0; si < 2; ++si)
                af[si] = *(const short8*)&As[mw + 16 * si + qr][kh * 32 + quad * 8];
            #pragma unroll
            for (int sj = 0; sj < 4; ++sj)
                bf[sj] = *(const short8*)&Bs[nw + 16 * sj + qr][kh * 32 + quad * 8];
            #pragma unroll
            for (int si = 0; si < 2; ++si)
                #pragma unroll
                for (int sj = 0; sj < 4; ++sj)
                    acc[si][sj] = __builtin_amdgcn_mfma_f32_16x16x32_bf16(
                        af[si], bf[sj], acc[si][sj], 0, 0, 0);
        }
    }

    if (which == 0) {
        #pragma unroll
        for (int si = 0; si < 2; ++si) {
            #pragma unroll
            for (int sj = 0; sj < 4; ++sj) {
                const int col = n0 + nw + 16 * sj + qr;
                const int h = col >> 6, d = col & 63;
                #pragma unroll
                for (int r = 0; r < 4; ++r) {
                    const int row = m0 + mw + 16 * si + quad * 4 + r;
                    const int b = row >> 11, s = row & (SEQ - 1);
                    Oq[((size_t)(b * NH + h) * SEQ + s) * DQ + d] = f2bf(acc[si][sj][r] * QSCALE);
                }
            }
        }
    } else if (which == 1) {
        #pragma unroll
        for (int si = 0; si < 2; ++si) {
            #pragma unroll
            for (int sj = 0; sj < 4; ++sj) {
                const int col = n0 + nw + 16 * sj + qr;
                const int h = col >> 6, d = col & 63;
                #pragma unroll
                for (int r = 0; r < 4; ++r) {
                    const int row = m0 + mw + 16 * si + quad * 4 + r;
                    const int b = row >> 11, s = row & (SEQ - 1);
                    // Kf fragment-major
                    Ok[(size_t)(b * NH + h) * (SEQ * DQ)
                       + (size_t)(((s >> 5) * 4 + (d >> 4)) << 9)
                       + ((((d >> 3) & 1) << 5) + (s & 31)) * 8 + (d & 7)] = f2bf(acc[si][sj][r]);
                }
            }
        }
    } else {
        #pragma unroll
        for (int si = 0; si < 2; ++si) {
            #pragma unroll
            for (int sj = 0; sj < 4; ++sj) {
                const int col = n0 + nw + 16 * sj + qr;
                const int h = col >> 6, d = col & 63;
                #pragma unroll
                for (int r = 0; r < 4; ++r) {
                    const int row = m0 + mw + 16 * si + quad * 4 + r;
                    const int b = row >> 11, s = row & (SEQ - 1);
                    // Vf fragment-major
                    Ovt[(size_t)(b * NH + h) * (SEQ * DQ)
                        + (size_t)((s >> 6) << 12) + (((s >> 5) & 1) << 11)
                        + ((d >> 5) << 10) + (((s >> 4) & 1) << 9)
                        + ((((s >> 3) & 1) << 5) + (d & 31)) * 8 + (s & 7)] = f2bf(acc[si][sj][r]);
                }
            }
        }
    }
}

// ---------------------------------------------------------------------------
// out GEMM (v12): 64x64 tile, grid (128,8) = 1024 blocks -> 4 blocks/CU.
// ---------------------------------------------------------------------------
__global__ __launch_bounds__(256) void out_gemm_kernel(
    const unsigned short* __restrict__ A, const unsigned short* __restrict__ Bt,
    float* __restrict__ C)
{
    __shared__ unsigned short As[64][APAD];
    __shared__ unsigned short Bs[64][APAD];

    const int m0 = blockIdx.x * 64;
    const int n0 = blockIdx.y * 64;
    const int t = threadIdx.x, w = t >> 6, lane = t & 63;
    const int quad = lane >> 4, qr = lane & 15;
    const int brow = t >> 3;           // 32 rows/pass, 2 passes
    const int bcol = (t & 7) * 8;
    const int mw = 32 * (w >> 1), nw = 32 * (w & 1);

    floatx4 acc[2][2] = {};
    ushort8 areg[2], breg[2];

    #pragma unroll
    for (int i = 0; i < 2; ++i) {
        areg[i] = *(const ushort8*)(A + (size_t)(m0 + i * 32 + brow) * DM + bcol);
        breg[i] = *(const ushort8*)(Bt + (size_t)(n0 + i * 32 + brow) * DM + bcol);
    }

    for (int k0 = 0; k0 < DM; k0 += 64) {
        __syncthreads();
        #pragma unroll
        for (int i = 0; i < 2; ++i) {
            *(ushort8*)&As[i * 32 + brow][bcol] = areg[i];
            *(ushort8*)&Bs[i * 32 + brow][bcol] = breg[i];
        }
        __syncthreads();

        if (k0 + 64 < DM) {
            #pragma unroll
            for (int i = 0; i < 2; ++i) {
                areg[i] = *(const ushort8*)(A + (size_t)(m0 + i * 32 + brow) * DM + k0 + 64 + bcol);
                breg[i] = *(const ushort8*)(Bt + (size_t)(n0 + i * 32 + brow) * DM + k0 + 64 + bcol);
            }
        }

        #pragma unroll
        for (int kh = 0; kh < 2; ++kh) {
            short8 af[2], bf[2];
            #pragma unroll
            for (int si = 0; si < 2; ++si)
                af[si] = *(const short8*)&As[mw + 16 * si + qr][kh * 32 + quad * 8];
            #pragma unroll
            for (int sj = 0; sj < 2; ++sj)
                bf[sj] = *(const short8*)&Bs[nw + 16 * sj + qr][kh * 32 + quad * 8];
            #pragma unroll
            for (int si = 0; si < 2; ++si)
                #pragma unroll
                for (int sj = 0; sj < 2; ++sj)
                    acc[si][sj] = __builtin_amdgcn_mfma_f32_16x16x32_bf16(
                        af[si], bf[sj], acc[si][sj], 0, 0, 0);
        }
    }

    #pragma unroll
    for (int si = 0; si < 2; ++si) {
        #pragma unroll
        for (int sj = 0; sj < 2; ++sj) {
            const int col = n0 + nw + 16 * sj + qr;
            #pragma unroll
            for (int r = 0; r < 4; ++r) {
                const int row = m0 + mw + 16 * si + quad * 4 + r;
                C[(size_t)row * DM + col] = acc[si][sj][r];
            }
        }
    }
}

// ---------------------------------------------------------------------------
// flash attention v13: QBLK 64 -> 128 (8 waves, 512 threads, grid 512).
// v12 model: each block streams its head's full K/V (512 KB) from L2; 1024
// blocks -> 512 MB L2 reads = ~15 us/XCD floor at 4.3 TB/s -- the dominant
// non-VALU cost (no pipe >45% busy, conflicts 0, HBM 5%). Halving the block
// count halves the K/V L2 stream (256 MB), and 2 blocks/CU (2 heads) puts
// the per-iter K/V working set (24 KB) under the 32 KB L1 so the 4 waves
// sharing each fragment can L1-hit. Waves/CU unchanged (16) -> same latency
// hiding. Per-wave loop is byte-identical to v11/v12 (single variable).
// Epilogue: Obuf 128x66 + lbuf -> 34.8 KB LDS, fine at 2 blocks/CU.
// XCD decode bijective: 512 = 8 xcd x 4 bh x 16 tiles.
// grid = (512), block 512, __launch_bounds__(512,2) (VGPR cap 256, no spill).
// MFMA 32x32x16 layouts: A[m=lane&31][k=(lane>>5)*8+j],
// B[k=(lane>>5)*8+j][n=lane&31], C/D col=lane&31,
// row=(reg&3)+8*(reg>>2)+4*(lane>>5)  (HW-verified m74/m101).
// ---------------------------------------------------------------------------
__global__ __launch_bounds__(512, 2) void attn_kernel(
    const unsigned short* __restrict__ Qp, const unsigned short* __restrict__ Kf,
    const unsigned short* __restrict__ Vf, unsigned short* __restrict__ Hd)
{
    __shared__ float epi[128 * 66 + 256];   // Obuf 128x66 + lbuf: 34.8 KB

    // XCD-aware decode: xcd = f&7 (round-robin dispatch), each XCD owns
    // 4 complete bh-groups (512 % 8 == 0 -> bijective).
    const int f    = blockIdx.x;
    const int xcd  = f & 7;
    const int slot = f >> 3;            // 0..63 within XCD
    const int tile = slot & 15;         // q-tile (128 rows)
    const int bhi  = (slot >> 4) * 8 + xcd;   // 0..31
    const int b = bhi >> 3, h = bhi & 7;

    const int s0 = tile * 128;
    const size_t bh   = (size_t)(b * NH + h);
    const size_t base = bh * SEQ * DQ;

    const int t    = threadIdx.x;
    const int w    = t >> 6;      // 0..7
    const int lane = t & 63;
    const int qh   = w >> 1;      // q-quarter (rows 32qh..32qh+31 of 128)
    const int kh   = w & 1;       // kv-half within each 64-kv tile
    const int ln31 = lane & 31;
    const int lh   = lane >> 5;   // lane half

    // ---- Q B-fragments direct from global (once): B[k=d][n=q] ----
    short8 bq[4];
    {
        const unsigned short* gq = Qp + base + (size_t)(s0 + 32 * qh + ln31) * DQ + lh * 8;
        #pragma unroll
        for (int s = 0; s < 4; ++s)
            bq[s] = *(const short8*)(gq + 16 * s);
    }

    // fragment-major stream pointers: everything is base + lane*16B
    const unsigned short* pK = Kf + base + ((size_t)kh << 11) + (size_t)lane * 8;
    const unsigned short* pV = Vf + base + ((size_t)kh << 11) + (size_t)lane * 8;

    floatx16 accO[2] = {};   // partial O[32q][64dv]: a=dv-block; lane col=dv
    float l_lane = 0.f;

    // ---- prologue: fragment loads for kt=0 ----
    short8 ak[4], bv[4];
    #pragma unroll
    for (int s = 0; s < 4; ++s)
        ak[s] = *(const short8*)(pK + s * 512);
    #pragma unroll
    for (int a = 0; a < 2; ++a)
        #pragma unroll
        for (int s = 0; s < 2; ++s)
            bv[a * 2 + s] = *(const short8*)(pV + a * 1024 + s * 512);

    for (int kt = 0; kt < SEQ; kt += 64) {
        // ---- S^T[32kv][32q] = K-half @ Q-quarter^T (4-chain over d=64) ----
        floatx16 z = {};
        __builtin_amdgcn_s_setprio(1);
        #pragma unroll
        for (int s = 0; s < 4; ++s)
            z = __builtin_amdgcn_mfma_f32_32x32x16_bf16(ak[s], bq[s], z, 0, 0, 0);
        __builtin_amdgcn_s_setprio(0);

        // ---- prefetch next ak (regs free after QK; lands during softmax+PV) ----
        const int ktn = (kt + 64 < SEQ) ? kt + 64 : kt;
        {
            const unsigned short* nK = pK + ((size_t)(ktn >> 5) << 11);
            #pragma unroll
            for (int s = 0; s < 4; ++s)
                ak[s] = *(const short8*)(nK + s * 512);
        }

        // ---- exp2, l accumulate, pack P (reg 4g+j -> kv = 8g+4lh+j) ----
        unsigned wg[4][2];
        #pragma unroll
        for (int g = 0; g < 4; ++g) {
            const float p0 = __builtin_amdgcn_exp2f(z[4 * g + 0]);
            const float p1 = __builtin_amdgcn_exp2f(z[4 * g + 1]);
            const float p2 = __builtin_amdgcn_exp2f(z[4 * g + 2]);
            const float p3 = __builtin_amdgcn_exp2f(z[4 * g + 3]);
            l_lane += (p0 + p1) + (p2 + p3);
            wg[g][0] = pack2bf(p0, p1);
            wg[g][1] = pack2bf(p2, p3);
        }

        // ---- T12: build PV A-fragments in-register via permlane32_swap ----
        const uintx2 e0 = __builtin_amdgcn_permlane32_swap(wg[0][0], wg[1][0], false, false);
        const uintx2 e1 = __builtin_amdgcn_permlane32_swap(wg[0][1], wg[1][1], false, false);
        const uintx2 e2 = __builtin_amdgcn_permlane32_swap(wg[2][0], wg[3][0], false, false);
        const uintx2 e3 = __builtin_amdgcn_permlane32_swap(wg[2][1], wg[3][1], false, false);
        uintx4 ua0, ua1;
        ua0[0] = e0[0]; ua0[1] = e1[0]; ua0[2] = e0[1]; ua0[3] = e1[1];
        ua1[0] = e2[0]; ua1[1] = e3[0]; ua1[2] = e2[1]; ua1[3] = e3[1];
        const short8 ap0 = __builtin_bit_cast(short8, ua0);
        const short8 ap1 = __builtin_bit_cast(short8, ua1);

        // ---- PV: accO[a] += P[32q][32kv] @ V[32kv][32dv] ----
        __builtin_amdgcn_s_setprio(1);
        #pragma unroll
        for (int a = 0; a < 2; ++a) {
            accO[a] = __builtin_amdgcn_mfma_f32_32x32x16_bf16(ap0, bv[a * 2 + 0], accO[a], 0, 0, 0);
            accO[a] = __builtin_amdgcn_mfma_f32_32x32x16_bf16(ap1, bv[a * 2 + 1], accO[a], 0, 0, 0);
        }
        __builtin_amdgcn_s_setprio(0);

        // ---- prefetch next bv (regs free after PV; lands by next PV) ----
        {
            const unsigned short* nV = pV + ((size_t)(ktn >> 6) << 12);
            #pragma unroll
            for (int a = 0; a < 2; ++a)
                #pragma unroll
                for (int s = 0; s < 2; ++s)
                    bv[a * 2 + s] = *(const short8*)(nV + a * 1024 + s * 512);
        }
    }

    // ---- cross-kh combine: O and l, via epilogue-only LDS ----
    float l2 = l_lane + __shfl_xor(l_lane, 32);   // full kv-half sum for q=32qh+ln31
    float* Obuf = epi;                 // 128x66 f32
    float* lbuf = epi + 128 * 66;      // [0..127] kh0-l, [128..255] inv_l

    if (kh == 0) {
        if (lane < 32) lbuf[qh * 32 + lane] = l2;
        #pragma unroll
        for (int a = 0; a < 2; ++a)
            #pragma unroll
            for (int r = 0; r < 16; ++r) {
                const int qrow = (r & 3) + 8 * (r >> 2) + 4 * lh;
                Obuf[(32 * qh + qrow) * 66 + 32 * a + ln31] = accO[a][r];
            }
    }
    __syncthreads();

    if (kh == 1) {
        const float ltot = l2 + lbuf[qh * 32 + ln31];
        if (lane < 32) lbuf[128 + qh * 32 + lane] = 1.0f / ltot;  // same-wave RAW
        #pragma unroll
        for (int a = 0; a < 2; ++a)
            #pragma unroll
            for (int r = 0; r < 16; ++r) {
                const int qrow = (r & 3) + 8 * (r >> 2) + 4 * lh;
                const float o = accO[a][r] + Obuf[(32 * qh + qrow) * 66 + 32 * a + ln31];
                const float iv = lbuf[128 + qh * 32 + qrow];
                Hd[base + (size_t)(s0 + 32 * qh + qrow) * DQ + 32 * a + ln31] = f2bf(o * iv);
            }
    }
}

// ---------------------------------------------------------------------------
// kernel_launch
// Workspace (ushort units):
//   wt:    0        (3 x 262144)    qkv weights bf16, B^T [h*64+d][dd]
//   wo:    786432   (262144)        Wout bf16 [o][c]
//   q_ws:  1048576  (4194304)       q*QSCALE bf16 [b,h,s,d]
//   k_ws:  5242880  (4194304)       k bf16 fragment-major Kf
//   vt_ws: 9437184  (4194304)       v bf16 fragment-major Vf
//   h_ws:  13631488 (4194304)       heads bf16 (flat GEMM-A view)
// total ~34 MB
// ---------------------------------------------------------------------------
extern "C" void kernel_launch(void* const* d_in, const int* in_sizes, int n_in,
                              void* d_out, int out_size, void* d_ws, size_t ws_size,
                              hipStream_t stream) {
    const float* xq = (const float*)d_in[0];
    const float* xk = (const float*)d_in[1];
    const float* xv = (const float*)d_in[2];
    const float* Qw = (const float*)d_in[3];
    const float* Kw = (const float*)d_in[4];
    const float* Vw = (const float*)d_in[5];
    const float* Wo = (const float*)d_in[6];
    float* out = (float*)d_out;

    unsigned short* ws = (unsigned short*)d_ws;
    unsigned short* wt    = ws;
    unsigned short* wo    = ws + (size_t)786432;
    unsigned short* q_ws  = ws + (size_t)1048576;
    unsigned short* k_ws  = ws + (size_t)5242880;
    unsigned short* vt_ws = ws + (size_t)9437184;
    unsigned short* h_ws  = ws + (size_t)13631488;

    convert_w_kernel<<<dim3(256, 4), 256, 0, stream>>>(Qw, Kw, Vw, Wo, wt, wo);
    qkv_gemm_kernel<<<dim3(128, 4, 3), 256, 0, stream>>>(xq, xk, xv, wt, q_ws, k_ws, vt_ws);
    attn_kernel<<<dim3(512), 512, 0, stream>>>(q_ws, k_ws, vt_ws, h_ws);
    out_gemm_kernel<<<dim3(128, 8), 256, 0, stream>>>(h_ws, wo, out);
}

// Round 8
// 180.473 us; speedup vs baseline: 1.0025x; 1.0025x over previous
//
#include <hip/hip_runtime.h>
#include <math.h>

// Problem constants (B=4, S=2048, D_MODEL=512, H=8, DQ=64)
#define BATCH 4
#define SEQ   2048
#define DM    512
#define NH    8
#define DQ    64
#define BS    (BATCH*SEQ)     // 8192 rows
#define APAD  72              // padded tile stride in gemms

// q pre-scale: 1/sqrt(64) * log2(e), so softmax uses native 2^x (v_exp_f32)
#define QSCALE 0.18033688011112042f

typedef short  short8   __attribute__((ext_vector_type(8)));
typedef float  floatx4  __attribute__((ext_vector_type(4)));
typedef float  floatx16 __attribute__((ext_vector_type(16)));
typedef unsigned short ushort8 __attribute__((ext_vector_type(8)));
typedef unsigned uintx2 __attribute__((ext_vector_type(2)));
typedef unsigned uintx4 __attribute__((ext_vector_type(4)));

// cheap bf16: round-half-up (1 add + shift). Ties-only delta vs RNE.
__device__ __forceinline__ unsigned short f2bf(float f) {
    return (unsigned short)((__float_as_uint(f) + 0x8000u) >> 16);
}
// pack two floats -> two bf16 in one u32 (lo = a, hi = b): 2 adds + 1 v_perm
__device__ __forceinline__ unsigned pack2bf(float a, float b) {
    unsigned ua = __float_as_uint(a) + 0x8000u;
    unsigned ub = __float_as_uint(b) + 0x8000u;
    return __builtin_amdgcn_perm(ub, ua, 0x07060302u);  // {ub[3],ub[2],ua[3],ua[2]}
}
// HW packed f32->2xbf16 (RNE), 1 VALU op: lo = cvt(a), hi = cvt(b)
__device__ __forceinline__ unsigned cvtpk(float a, float b) {
    unsigned r;
    asm("v_cvt_pk_bf16_f32 %0, %1, %2" : "=v"(r) : "v"(a), "v"(b));
    return r;
}

// ---------------------------------------------------------------------------
// convert_w: COALESCED reads for the qkv projections (v12).
// grid (256, 4).
// ---------------------------------------------------------------------------
__global__ __launch_bounds__(256) void convert_w_kernel(
    const float* __restrict__ Wq, const float* __restrict__ Wk,
    const float* __restrict__ Wv, const float* __restrict__ Wo,
    unsigned short* __restrict__ wt, unsigned short* __restrict__ wo)
{
    const int which = blockIdx.y;
    const int idx = blockIdx.x * 256 + threadIdx.x;   // 65536 per matrix
    if (which == 3) {
        float4 v = *(const float4*)(Wo + (size_t)idx * 4);
        uint2 o;
        o.x = pack2bf(v.x, v.y);
        o.y = pack2bf(v.z, v.w);
        *(uint2*)(wo + (size_t)idx * 4) = o;
    } else {
        const float* W = (which == 0) ? Wq : (which == 1) ? Wk : Wv;
        const int n   = idx & 511;         // h*64+d  (consecutive per lane)
        const int dd0 = (idx >> 9) * 4;    // 0..508
        const int h = n >> 6, d = n & 63;
        uint2 o;
        o.x = pack2bf(W[((size_t)h * DM + dd0 + 0) * DQ + d],
                      W[((size_t)h * DM + dd0 + 1) * DQ + d]);
        o.y = pack2bf(W[((size_t)h * DM + dd0 + 2) * DQ + d],
                      W[((size_t)h * DM + dd0 + 3) * DQ + d]);
        *(uint2*)(wt + (size_t)which * (DM * DM) + (size_t)n * DM + dd0) = o;
    }
}

// ---------------------------------------------------------------------------
// qkv GEMM (v12): 64x128 tile, BK=64, K=512. 4 blocks/CU.
// Outputs:
//   which 0 -> q*QSCALE bf16 [b,h,s,d]
//   which 1 -> k bf16 FRAGMENT-MAJOR Kf  [bh][s>>5][d>>4][lane][8]
//   which 2 -> v bf16 FRAGMENT-MAJOR Vf  [bh][s>>6][(s>>5)&1][d>>5][(s>>4)&1][lane][8]
// grid (128, 4, 3), block 256 (4 waves, 2x2; wave tile 32x64).
// ---------------------------------------------------------------------------
__global__ __launch_bounds__(256) void qkv_gemm_kernel(
    const float* __restrict__ Xq, const float* __restrict__ Xk,
    const float* __restrict__ Xv, const unsigned short* __restrict__ wt,
    unsigned short* __restrict__ Oq, unsigned short* __restrict__ Ok,
    unsigned short* __restrict__ Ovt)
{
    __shared__ unsigned short As[64][APAD];
    __shared__ unsigned short Bs[128][APAD];

    const int which = blockIdx.z;
    const float* X = (which == 0) ? Xq : (which == 1) ? Xk : Xv;
    const unsigned short* Bt = wt + (size_t)which * (DM * DM);

    const int m0 = blockIdx.x * 64;
    const int n0 = blockIdx.y * 128;
    const int t = threadIdx.x, w = t >> 6, lane = t & 63;
    const int quad = lane >> 4, qr = lane & 15;
    const int arow = t >> 4;           // A staging: 16 rows/pass, 4 passes
    const int acol = (t & 15) * 4;     // float4 col
    const int brow = t >> 3;           // B staging: 32 rows/pass, 4 passes
    const int bcol = (t & 7) * 8;      // ushort8 col
    const int mw = 32 * (w >> 1), nw = 64 * (w & 1);

    floatx4 acc[2][4] = {};
    float4  areg[4];
    ushort8 breg[4];

    #pragma unroll
    for (int i = 0; i < 4; ++i)
        areg[i] = *(const float4*)(X + (size_t)(m0 + i * 16 + arow) * DM + acol);
    #pragma unroll
    for (int i = 0; i < 4; ++i)
        breg[i] = *(const ushort8*)(Bt + (size_t)(n0 + i * 32 + brow) * DM + bcol);

    for (int k0 = 0; k0 < DM; k0 += 64) {
        __syncthreads();
        #pragma unroll
        for (int i = 0; i < 4; ++i) {
            uint2 o;
            o.x = pack2bf(areg[i].x, areg[i].y);
            o.y = pack2bf(areg[i].z, areg[i].w);
            *(uint2*)&As[i * 16 + arow][acol] = o;
        }
        #pragma unroll
        for (int i = 0; i < 4; ++i)
            *(ushort8*)&Bs[i * 32 + brow][bcol] = breg[i];
        __syncthreads();

        if (k0 + 64 < DM) {
            #pragma unroll
            for (int i = 0; i < 4; ++i)
                areg[i] = *(const float4*)(X + (size_t)(m0 + i * 16 + arow) * DM + k0 + 64 + acol);
            #pragma unroll
            for (int i = 0; i < 4; ++i)
                breg[i] = *(const ushort8*)(Bt + (size_t)(n0 + i * 32 + brow) * DM + k0 + 64 + bcol);
        }

        #pragma unroll
        for (int kh = 0; kh < 2; ++kh) {
            short8 af[2], bf[4];
            #pragma unroll
            for (int si = 0; si < 2; ++si)
                af[si] = *(const short8*)&As[mw + 16 * si + qr][kh * 32 + quad * 8];
            #pragma unroll
            for (int sj = 0; sj < 4; ++sj)
                bf[sj] = *(const short8*)&Bs[nw + 16 * sj + qr][kh * 32 + quad * 8];
            #pragma unroll
            for (int si = 0; si < 2; ++si)
                #pragma unroll
                for (int sj = 0; sj < 4; ++sj)
                    acc[si][sj] = __builtin_amdgcn_mfma_f32_16x16x32_bf16(
                        af[si], bf[sj], acc[si][sj], 0, 0, 0);
        }
    }

    if (which == 0) {
        #pragma unroll
        for (int si = 0; si < 2; ++si) {
            #pragma unroll
            for (int sj = 0; sj < 4; ++sj) {
                const int col = n0 + nw + 16 * sj + qr;
                const int h = col >> 6, d = col & 63;
                #pragma unroll
                for (int r = 0; r < 4; ++r) {
                    const int row = m0 + mw + 16 * si + quad * 4 + r;
                    const int b = row >> 11, s = row & (SEQ - 1);
                    Oq[((size_t)(b * NH + h) * SEQ + s) * DQ + d] = f2bf(acc[si][sj][r] * QSCALE);
                }
            }
        }
    } else if (which == 1) {
        #pragma unroll
        for (int si = 0; si < 2; ++si) {
            #pragma unroll
            for (int sj = 0; sj < 4; ++sj) {
                const int col = n0 + nw + 16 * sj + qr;
                const int h = col >> 6, d = col & 63;
                #pragma unroll
                for (int r = 0; r < 4; ++r) {
                    const int row = m0 + mw + 16 * si + quad * 4 + r;
                    const int b = row >> 11, s = row & (SEQ - 1);
                    // Kf fragment-major
                    Ok[(size_t)(b * NH + h) * (SEQ * DQ)
                       + (size_t)(((s >> 5) * 4 + (d >> 4)) << 9)
                       + ((((d >> 3) & 1) << 5) + (s & 31)) * 8 + (d & 7)] = f2bf(acc[si][sj][r]);
                }
            }
        }
    } else {
        #pragma unroll
        for (int si = 0; si < 2; ++si) {
            #pragma unroll
            for (int sj = 0; sj < 4; ++sj) {
                const int col = n0 + nw + 16 * sj + qr;
                const int h = col >> 6, d = col & 63;
                #pragma unroll
                for (int r = 0; r < 4; ++r) {
                    const int row = m0 + mw + 16 * si + quad * 4 + r;
                    const int b = row >> 11, s = row & (SEQ - 1);
                    // Vf fragment-major
                    Ovt[(size_t)(b * NH + h) * (SEQ * DQ)
                        + (size_t)((s >> 6) << 12) + (((s >> 5) & 1) << 11)
                        + ((d >> 5) << 10) + (((s >> 4) & 1) << 9)
                        + ((((s >> 3) & 1) << 5) + (d & 31)) * 8 + (s & 7)] = f2bf(acc[si][sj][r]);
                }
            }
        }
    }
}

// ---------------------------------------------------------------------------
// out GEMM (v12): 64x64 tile, grid (128,8) = 1024 blocks -> 4 blocks/CU.
// ---------------------------------------------------------------------------
__global__ __launch_bounds__(256) void out_gemm_kernel(
    const unsigned short* __restrict__ A, const unsigned short* __restrict__ Bt,
    float* __restrict__ C)
{
    __shared__ unsigned short As[64][APAD];
    __shared__ unsigned short Bs[64][APAD];

    const int m0 = blockIdx.x * 64;
    const int n0 = blockIdx.y * 64;
    const int t = threadIdx.x, w = t >> 6, lane = t & 63;
    const int quad = lane >> 4, qr = lane & 15;
    const int brow = t >> 3;           // 32 rows/pass, 2 passes
    const int bcol = (t & 7) * 8;
    const int mw = 32 * (w >> 1), nw = 32 * (w & 1);

    floatx4 acc[2][2] = {};
    ushort8 areg[2], breg[2];

    #pragma unroll
    for (int i = 0; i < 2; ++i) {
        areg[i] = *(const ushort8*)(A + (size_t)(m0 + i * 32 + brow) * DM + bcol);
        breg[i] = *(const ushort8*)(Bt + (size_t)(n0 + i * 32 + brow) * DM + bcol);
    }

    for (int k0 = 0; k0 < DM; k0 += 64) {
        __syncthreads();
        #pragma unroll
        for (int i = 0; i < 2; ++i) {
            *(ushort8*)&As[i * 32 + brow][bcol] = areg[i];
            *(ushort8*)&Bs[i * 32 + brow][bcol] = breg[i];
        }
        __syncthreads();

        if (k0 + 64 < DM) {
            #pragma unroll
            for (int i = 0; i < 2; ++i) {
                areg[i] = *(const ushort8*)(A + (size_t)(m0 + i * 32 + brow) * DM + k0 + 64 + bcol);
                breg[i] = *(const ushort8*)(Bt + (size_t)(n0 + i * 32 + brow) * DM + k0 + 64 + bcol);
            }
        }

        #pragma unroll
        for (int kh = 0; kh < 2; ++kh) {
            short8 af[2], bf[2];
            #pragma unroll
            for (int si = 0; si < 2; ++si)
                af[si] = *(const short8*)&As[mw + 16 * si + qr][kh * 32 + quad * 8];
            #pragma unroll
            for (int sj = 0; sj < 2; ++sj)
                bf[sj] = *(const short8*)&Bs[nw + 16 * sj + qr][kh * 32 + quad * 8];
            #pragma unroll
            for (int si = 0; si < 2; ++si)
                #pragma unroll
                for (int sj = 0; sj < 2; ++sj)
                    acc[si][sj] = __builtin_amdgcn_mfma_f32_16x16x32_bf16(
                        af[si], bf[sj], acc[si][sj], 0, 0, 0);
        }
    }

    #pragma unroll
    for (int si = 0; si < 2; ++si) {
        #pragma unroll
        for (int sj = 0; sj < 2; ++sj) {
            const int col = n0 + nw + 16 * sj + qr;
            #pragma unroll
            for (int r = 0; r < 4; ++r) {
                const int row = m0 + mw + 16 * si + quad * 4 + r;
                C[(size_t)row * DM + col] = acc[si][sj][r];
            }
        }
    }
}

// ---------------------------------------------------------------------------
// flash attention v14 = v13 + softmax VALU reduction.
// v13 post-mortem: attn invariant at 51-55 us across LDS-staged (v8),
// reg-direct (v11), and half-L2-stream (v13) -> per-wave serial dependency
// chain is the bottleneck (VALUBusy 41%, ~390 VALU cyc/wave-iter). v14 cuts
// VALU ops on the chain:
//  - l via MFMA-with-ones: accL = mfma(ap1,1, mfma(ap0,1, accL)) replaces
//    12 v_add/iter + end shfl_xor + l LDS sharing. accL has the same C/D
//    row mapping as accO -> each lane holds l for exactly the qrows it
//    writes (no shuffle, no lbuf).
//  - v_cvt_pk_bf16_f32 (1 op, RNE) replaces pack2bf (3 ops) for P packing:
//    -16 VALU ops/iter.
// +16 AGPR (accL) -> ~108 unified regs, still 4 waves/SIMD.
// Everything else identical to v13: QBLK 128, 8 waves, grid 512,
// fragment-major K/V, zero in-loop LDS/barriers, T1/T5/T12.
// MFMA 32x32x16 layouts: A[m=lane&31][k=(lane>>5)*8+j],
// B[k=(lane>>5)*8+j][n=lane&31], C/D col=lane&31,
// row=(reg&3)+8*(reg>>2)+4*(lane>>5)  (HW-verified m74/m101).
// ---------------------------------------------------------------------------
__global__ __launch_bounds__(512, 2) void attn_kernel(
    const unsigned short* __restrict__ Qp, const unsigned short* __restrict__ Kf,
    const unsigned short* __restrict__ Vf, unsigned short* __restrict__ Hd)
{
    __shared__ float epi[128 * 66 + 128];   // Obuf 128x66 + lbuf[128]

    // XCD-aware decode: xcd = f&7 (round-robin dispatch), each XCD owns
    // 4 complete bh-groups (512 % 8 == 0 -> bijective).
    const int f    = blockIdx.x;
    const int xcd  = f & 7;
    const int slot = f >> 3;            // 0..63 within XCD
    const int tile = slot & 15;         // q-tile (128 rows)
    const int bhi  = (slot >> 4) * 8 + xcd;   // 0..31
    const int b = bhi >> 3, h = bhi & 7;

    const int s0 = tile * 128;
    const size_t bh   = (size_t)(b * NH + h);
    const size_t base = bh * SEQ * DQ;

    const int t    = threadIdx.x;
    const int w    = t >> 6;      // 0..7
    const int lane = t & 63;
    const int qh   = w >> 1;      // q-quarter (rows 32qh..32qh+31 of 128)
    const int kh   = w & 1;       // kv-half within each 64-kv tile
    const int ln31 = lane & 31;
    const int lh   = lane >> 5;   // lane half

    // ---- Q B-fragments direct from global (once): B[k=d][n=q] ----
    short8 bq[4];
    {
        const unsigned short* gq = Qp + base + (size_t)(s0 + 32 * qh + ln31) * DQ + lh * 8;
        #pragma unroll
        for (int s = 0; s < 4; ++s)
            bq[s] = *(const short8*)(gq + 16 * s);
    }

    // all-ones bf16 B fragment for l row-sums
    short8 vones;
    #pragma unroll
    for (int i = 0; i < 8; ++i) vones[i] = (short)0x3F80;

    // fragment-major stream pointers: everything is base + lane*16B
    const unsigned short* pK = Kf + base + ((size_t)kh << 11) + (size_t)lane * 8;
    const unsigned short* pV = Vf + base + ((size_t)kh << 11) + (size_t)lane * 8;

    floatx16 accO[2] = {};   // partial O[32q][64dv]: a=dv-block; lane col=dv
    floatx16 accL   = {};    // partial l[32q] replicated over cols

    // ---- prologue: fragment loads for kt=0 ----
    short8 ak[4], bv[4];
    #pragma unroll
    for (int s = 0; s < 4; ++s)
        ak[s] = *(const short8*)(pK + s * 512);
    #pragma unroll
    for (int a = 0; a < 2; ++a)
        #pragma unroll
        for (int s = 0; s < 2; ++s)
            bv[a * 2 + s] = *(const short8*)(pV + a * 1024 + s * 512);

    for (int kt = 0; kt < SEQ; kt += 64) {
        // ---- S^T[32kv][32q] = K-half @ Q-quarter^T (4-chain over d=64) ----
        floatx16 z = {};
        __builtin_amdgcn_s_setprio(1);
        #pragma unroll
        for (int s = 0; s < 4; ++s)
            z = __builtin_amdgcn_mfma_f32_32x32x16_bf16(ak[s], bq[s], z, 0, 0, 0);
        __builtin_amdgcn_s_setprio(0);

        // ---- prefetch next ak (regs free after QK; lands during softmax+PV) ----
        const int ktn = (kt + 64 < SEQ) ? kt + 64 : kt;
        {
            const unsigned short* nK = pK + ((size_t)(ktn >> 5) << 11);
            #pragma unroll
            for (int s = 0; s < 4; ++s)
                ak[s] = *(const short8*)(nK + s * 512);
        }

        // ---- exp2 + packed bf16 convert (reg 4g+j -> kv = 8g+4lh+j) ----
        unsigned wg[4][2];
        #pragma unroll
        for (int g = 0; g < 4; ++g) {
            const float p0 = __builtin_amdgcn_exp2f(z[4 * g + 0]);
            const float p1 = __builtin_amdgcn_exp2f(z[4 * g + 1]);
            const float p2 = __builtin_amdgcn_exp2f(z[4 * g + 2]);
            const float p3 = __builtin_amdgcn_exp2f(z[4 * g + 3]);
            wg[g][0] = cvtpk(p0, p1);
            wg[g][1] = cvtpk(p2, p3);
        }

        // ---- T12: build PV A-fragments in-register via permlane32_swap ----
        const uintx2 e0 = __builtin_amdgcn_permlane32_swap(wg[0][0], wg[1][0], false, false);
        const uintx2 e1 = __builtin_amdgcn_permlane32_swap(wg[0][1], wg[1][1], false, false);
        const uintx2 e2 = __builtin_amdgcn_permlane32_swap(wg[2][0], wg[3][0], false, false);
        const uintx2 e3 = __builtin_amdgcn_permlane32_swap(wg[2][1], wg[3][1], false, false);
        uintx4 ua0, ua1;
        ua0[0] = e0[0]; ua0[1] = e1[0]; ua0[2] = e0[1]; ua0[3] = e1[1];
        ua1[0] = e2[0]; ua1[1] = e3[0]; ua1[2] = e2[1]; ua1[3] = e3[1];
        const short8 ap0 = __builtin_bit_cast(short8, ua0);
        const short8 ap1 = __builtin_bit_cast(short8, ua1);

        // ---- PV + l row-sums: accO[a] += P @ V; accL += P @ 1 ----
        __builtin_amdgcn_s_setprio(1);
        #pragma unroll
        for (int a = 0; a < 2; ++a) {
            accO[a] = __builtin_amdgcn_mfma_f32_32x32x16_bf16(ap0, bv[a * 2 + 0], accO[a], 0, 0, 0);
            accO[a] = __builtin_amdgcn_mfma_f32_32x32x16_bf16(ap1, bv[a * 2 + 1], accO[a], 0, 0, 0);
        }
        accL = __builtin_amdgcn_mfma_f32_32x32x16_bf16(ap0, vones, accL, 0, 0, 0);
        accL = __builtin_amdgcn_mfma_f32_32x32x16_bf16(ap1, vones, accL, 0, 0, 0);
        __builtin_amdgcn_s_setprio(0);

        // ---- prefetch next bv (regs free after PV; lands by next PV) ----
        {
            const unsigned short* nV = pV + ((size_t)(ktn >> 6) << 12);
            #pragma unroll
            for (int a = 0; a < 2; ++a)
                #pragma unroll
                for (int s = 0; s < 2; ++s)
                    bv[a * 2 + s] = *(const short8*)(nV + a * 1024 + s * 512);
        }
    }

    // ---- cross-kh combine: O via LDS, l via accL (lane-local rows) ----
    float* Obuf = epi;                 // 128x66 f32
    float* lbuf = epi + 128 * 66;      // [0..127] kh0 partial l per qrow

    if (kh == 0) {
        if (ln31 == 0) {
            #pragma unroll
            for (int r = 0; r < 16; ++r) {
                const int qrow = (r & 3) + 8 * (r >> 2) + 4 * lh;
                lbuf[32 * qh + qrow] = accL[r];
            }
        }
        #pragma unroll
        for (int a = 0; a < 2; ++a)
            #pragma unroll
            for (int r = 0; r < 16; ++r) {
                const int qrow = (r & 3) + 8 * (r >> 2) + 4 * lh;
                Obuf[(32 * qh + qrow) * 66 + 32 * a + ln31] = accO[a][r];
            }
    }
    __syncthreads();

    if (kh == 1) {
        float inv[16];
        #pragma unroll
        for (int r = 0; r < 16; ++r) {
            const int qrow = (r & 3) + 8 * (r >> 2) + 4 * lh;
            inv[r] = 1.0f / (accL[r] + lbuf[32 * qh + qrow]);
        }
        #pragma unroll
        for (int a = 0; a < 2; ++a)
            #pragma unroll
            for (int r = 0; r < 16; ++r) {
                const int qrow = (r & 3) + 8 * (r >> 2) + 4 * lh;
                const float o = accO[a][r] + Obuf[(32 * qh + qrow) * 66 + 32 * a + ln31];
                Hd[base + (size_t)(s0 + 32 * qh + qrow) * DQ + 32 * a + ln31] = f2bf(o * inv[r]);
            }
    }
}

// ---------------------------------------------------------------------------
// kernel_launch
// Workspace (ushort units):
//   wt:    0        (3 x 262144)    qkv weights bf16, B^T [h*64+d][dd]
//   wo:    786432   (262144)        Wout bf16 [o][c]
//   q_ws:  1048576  (4194304)       q*QSCALE bf16 [b,h,s,d]
//   k_ws:  5242880  (4194304)       k bf16 fragment-major Kf
//   vt_ws: 9437184  (4194304)       v bf16 fragment-major Vf
//   h_ws:  13631488 (4194304)       heads bf16 (flat GEMM-A view)
// total ~34 MB
// ---------------------------------------------------------------------------
extern "C" void kernel_launch(void* const* d_in, const int* in_sizes, int n_in,
                              void* d_out, int out_size, void* d_ws, size_t ws_size,
                              hipStream_t stream) {
    const float* xq = (const float*)d_in[0];
    const float* xk = (const float*)d_in[1];
    const float* xv = (const float*)d_in[2];
    const float* Qw = (const float*)d_in[3];
    const float* Kw = (const float*)d_in[4];
    const float* Vw = (const float*)d_in[5];
    const float* Wo = (const float*)d_in[6];
    float* out = (float*)d_out;

    unsigned short* ws = (unsigned short*)d_ws;
    unsigned short* wt    = ws;
    unsigned short* wo    = ws + (size_t)786432;
    unsigned short* q_ws  = ws + (size_t)1048576;
    unsigned short* k_ws  = ws + (size_t)5242880;
    unsigned short* vt_ws = ws + (size_t)9437184;
    unsigned short* h_ws  = ws + (size_t)13631488;

    convert_w_kernel<<<dim3(256, 4), 256, 0, stream>>>(Qw, Kw, Vw, Wo, wt, wo);
    qkv_gemm_kernel<<<dim3(128, 4, 3), 256, 0, stream>>>(xq, xk, xv, wt, q_ws, k_ws, vt_ws);
    attn_kernel<<<dim3(512), 512, 0, stream>>>(q_ws, k_ws, vt_ws, h_ws);
    out_gemm_kernel<<<dim3(128, 8), 256, 0, stream>>>(h_ws, wo, out);
}